// Round 3
// baseline (2261.685 us; speedup 1.0000x reference)
//
#include <hip/hip_runtime.h>
#include <cstdint>
#include <cstddef>

typedef _Float16 half8 __attribute__((ext_vector_type(8)));
typedef float f32x4 __attribute__((ext_vector_type(4)));

#define S_LEN 2048
#define HDIM  256
#define BATCH 64
#define LROW  264   // LDS row stride in f16: dword stride 132 ≡ 4 (mod 32) -> uniform banks

__device__ __forceinline__ float tanh_fast(float x) {
    // tanh(x) = 1 - 2/(exp(2x)+1); graceful at +/-inf
    float e = __expf(2.0f * x);
    return 1.0f - 2.0f / (e + 1.0f);
}

// ---------------------------------------------------------------------------
// Kernel A: xp[m, h] = sum_i x[m, i] * Wxh[h, i] + bxh[h]   (unchanged)
// ---------------------------------------------------------------------------
__global__ void __launch_bounds__(256) xp_gemm(
    const float* __restrict__ x, const float* __restrict__ Wxh,
    const float* __restrict__ bxh, float* __restrict__ out) {
    __shared__ float As[32][68];
    __shared__ float Bs[32][68];

    const int tid = threadIdx.x;
    const int tx = tid & 15;
    const int ty = tid >> 4;
    const size_t m0 = (size_t)blockIdx.x * 64;
    const int n0 = blockIdx.y * 64;

    const int r = tid >> 3;
    const int c = (tid & 7) * 4;

    float bj[4];
#pragma unroll
    for (int j = 0; j < 4; j++) bj[j] = bxh[n0 + tx * 4 + j];

    float acc[4][4] = {};

    for (int k0 = 0; k0 < 256; k0 += 32) {
        float4 a0 = *(const float4*)&x[(m0 + r) * 256 + k0 + c];
        float4 a1 = *(const float4*)&x[(m0 + r + 32) * 256 + k0 + c];
        float4 b0 = *(const float4*)&Wxh[(size_t)(n0 + r) * 256 + k0 + c];
        float4 b1 = *(const float4*)&Wxh[(size_t)(n0 + r + 32) * 256 + k0 + c];

        __syncthreads();
        As[c + 0][r] = a0.x; As[c + 1][r] = a0.y; As[c + 2][r] = a0.z; As[c + 3][r] = a0.w;
        As[c + 0][r + 32] = a1.x; As[c + 1][r + 32] = a1.y; As[c + 2][r + 32] = a1.z; As[c + 3][r + 32] = a1.w;
        Bs[c + 0][r] = b0.x; Bs[c + 1][r] = b0.y; Bs[c + 2][r] = b0.z; Bs[c + 3][r] = b0.w;
        Bs[c + 0][r + 32] = b1.x; Bs[c + 1][r + 32] = b1.y; Bs[c + 2][r + 32] = b1.z; Bs[c + 3][r + 32] = b1.w;
        __syncthreads();

#pragma unroll
        for (int kk = 0; kk < 32; kk++) {
            float4 av = *(const float4*)&As[kk][ty * 4];
            float4 bv = *(const float4*)&Bs[kk][tx * 4];
            float aa[4] = {av.x, av.y, av.z, av.w};
            float bb[4] = {bv.x, bv.y, bv.z, bv.w};
#pragma unroll
            for (int i = 0; i < 4; i++)
#pragma unroll
                for (int j = 0; j < 4; j++)
                    acc[i][j] = fmaf(aa[i], bb[j], acc[i][j]);
        }
    }

#pragma unroll
    for (int i = 0; i < 4; i++) {
        float4 o;
        o.x = acc[i][0] + bj[0];
        o.y = acc[i][1] + bj[1];
        o.z = acc[i][2] + bj[2];
        o.w = acc[i][3] + bj[3];
        *(float4*)&out[(m0 + ty * 4 + i) * 256 + n0 + tx * 4] = o;
    }
}

// ---------------------------------------------------------------------------
// Kernel B (rewritten): MFMA recurrence. 4 WGs x 512 threads (8 waves).
// WG wg owns batches [wg*16, wg*16+16): per step a 16x256 @ 256x256 GEMM
// via mfma_f32_16x16x32_f16. Wave w owns output cols [w*32, w*32+32).
// W_hh B-fragments live in VGPRs (loaded once). h_t in LDS (f16,
// double-buffered, row stride 264 f16 -> uniform bank spread on
// ds_read_b128 A-fragment reads). One barrier per step. xp gathered from
// global 2 steps ahead into registers (2x unrolled reg sets).
// A/B fragments use the same k-map (k = kt*32 + 8*(lane>>4) + j), so any
// internal k-permutation cancels; C/D layout: col=lane&15, row=(lane>>4)*4+reg.
// ---------------------------------------------------------------------------
__global__ void __launch_bounds__(512, 1) rnn_mfma(
    const float* __restrict__ Whh, const float* __restrict__ bhh,
    float* __restrict__ out) {
    const int wg = blockIdx.x;      // 0..3
    const int t = threadIdx.x;
    const int w = t >> 6;           // wave 0..7
    const int l = t & 63;
    const int c = l & 15;           // col within 16-tile / A row
    const int g = l >> 4;           // k-group 0..3

    const int n0 = w * 32 + c;      // output col for nt=0; nt=1 adds 16

    __shared__ _Float16 hls[2][16][LROW];

    // ---- one-time: W_hh B-fragments into registers (f16) ----
    // wf[nt][kt] element j = B[k][n] = Whh[n][k], k = kt*32 + 8*g + j
    half8 wf[2][8];
#pragma unroll
    for (int nt = 0; nt < 2; nt++) {
        const float* wr = Whh + (size_t)(n0 + nt * 16) * HDIM;
#pragma unroll
        for (int kt = 0; kt < 8; kt++) {
            float4 u = *(const float4*)&wr[kt * 32 + 8 * g];
            float4 v = *(const float4*)&wr[kt * 32 + 8 * g + 4];
            half8 f;
            f[0] = (_Float16)u.x; f[1] = (_Float16)u.y;
            f[2] = (_Float16)u.z; f[3] = (_Float16)u.w;
            f[4] = (_Float16)v.x; f[5] = (_Float16)v.y;
            f[6] = (_Float16)v.z; f[7] = (_Float16)v.w;
            wf[nt][kt] = f;
        }
    }
    const float b0 = bhh[n0];
    const float b1 = bhh[n0 + 16];

    // ---- zero h_0 buffer ----
    for (int i = t; i < 16 * LROW; i += 512) (&hls[0][0][0])[i] = (_Float16)0.f;

    // per-batch-row output base pointers (this lane's 4 batch rows)
    float* bb[4];
#pragma unroll
    for (int r = 0; r < 4; r++)
        bb[r] = out + (size_t)(wg * 16 + 4 * g + r) * S_LEN * HDIM;
    float* hl = out + (size_t)BATCH * S_LEN * HDIM;

    // ---- prologue: xp for s=0 (set A) and s=1 (set B) ----
    f32x4 xA0, xA1, xB0, xB1;
#pragma unroll
    for (int r = 0; r < 4; r++) {
        xA0[r] = bb[r][n0];
        xA1[r] = bb[r][n0 + 16];
        xB0[r] = bb[r][HDIM + n0];
        xB1[r] = bb[r][HDIM + n0 + 16];
    }

    __syncthreads();

    int p = 0;
    auto phase = [&](int s, f32x4& xq0, f32x4& xq1) {
        // A fragments: h_t rows from hls[p] (16B contiguous per lane)
        half8 af[8];
#pragma unroll
        for (int kt = 0; kt < 8; kt++)
            af[kt] = *(const half8*)&hls[p][c][kt * 32 + 8 * g];

        // seed accumulators with xp + bias (C layout: row 4g+r, col n)
        f32x4 acc0, acc1;
#pragma unroll
        for (int r = 0; r < 4; r++) {
            acc0[r] = xq0[r] + b0;
            acc1[r] = xq1[r] + b1;
        }

        // prefetch xp for s+2 into this phase's reg set (2-step slack)
        const int sp = (s + 2 < S_LEN) ? s + 2 : S_LEN - 1;
#pragma unroll
        for (int r = 0; r < 4; r++) {
            xq0[r] = bb[r][(size_t)sp * HDIM + n0];
            xq1[r] = bb[r][(size_t)sp * HDIM + n0 + 16];
        }

#pragma unroll
        for (int kt = 0; kt < 8; kt++) {
            acc0 = __builtin_amdgcn_mfma_f32_16x16x32_f16(af[kt], wf[0][kt], acc0, 0, 0, 0);
            acc1 = __builtin_amdgcn_mfma_f32_16x16x32_f16(af[kt], wf[1][kt], acc1, 0, 0, 0);
        }

        // tanh, write h_seq (global), post h_{t+1} (LDS other buffer)
#pragma unroll
        for (int r = 0; r < 4; r++) {
            float v0 = tanh_fast(acc0[r]);
            float v1 = tanh_fast(acc1[r]);
            bb[r][(size_t)s * HDIM + n0] = v0;
            bb[r][(size_t)s * HDIM + n0 + 16] = v1;
            hls[p ^ 1][4 * g + r][n0] = (_Float16)v0;
            hls[p ^ 1][4 * g + r][n0 + 16] = (_Float16)v1;
            if (s == S_LEN - 1) {
                hl[(wg * 16 + 4 * g + r) * HDIM + n0] = v0;
                hl[(wg * 16 + 4 * g + r) * HDIM + n0 + 16] = v1;
            }
        }
        p ^= 1;
        __syncthreads();
    };

    for (int s = 0; s < S_LEN; s += 2) {
        phase(s, xA0, xA1);
        phase(s + 1, xB0, xB1);
    }
}

extern "C" void kernel_launch(void* const* d_in, const int* in_sizes, int n_in,
                              void* d_out, int out_size, void* d_ws, size_t ws_size,
                              hipStream_t stream) {
    const float* x   = (const float*)d_in[0];
    const float* Wxh = (const float*)d_in[1];
    const float* bxh = (const float*)d_in[2];
    const float* Whh = (const float*)d_in[3];
    const float* bhh = (const float*)d_in[4];
    float* out = (float*)d_out;

    dim3 gridA(131072 / 64, 256 / 64);  // (2048, 4)
    xp_gemm<<<gridA, 256, 0, stream>>>(x, Wxh, bxh, out);
    rnn_mfma<<<4, 512, 0, stream>>>(Whh, bhh, out);
}